// Round 14
// baseline (487.168 us; speedup 1.0000x reference)
//
#include <hip/hip_runtime.h>
#include <cstdint>
#include <cstddef>

#define ALPHA 0.2f
// N=8192, Fin=512, Fout=256 hard-coded per problem instance.

typedef __attribute__((ext_vector_type(8)))  short short8;   // 8 bf16 (4 VGPRs)
typedef __attribute__((ext_vector_type(16))) float f32x16;   // 32x32 MFMA acc

static __device__ __forceinline__ unsigned short f2bf(float x) {
  union { float f; unsigned u; } c; c.f = x;
  unsigned u = c.u;
  unsigned r = (u + 0x7FFFu + ((u >> 16) & 1u)) >> 16;  // RNE
  return (unsigned short)r;
}

// ------------- Kernel W: wa1/wa2 = W @ a1/a2  +  pack W into B-fragments ----
// b<8: wa path (64 rows of W each). b>=8 (32 blocks): WP pack, 8 frags each.
// WP[n32][k16][lane][e] = f2bf(W[k16*16 + (lane>>5)*8 + e][n32*32 + (lane&31)])
// -> gemm's B-load is one coalesced 1KB wave-load per fragment.
__global__ __launch_bounds__(256) void wa_wpack(const float* __restrict__ W,
                                                const float* __restrict__ a,
                                                float* __restrict__ wa1,
                                                float* __restrict__ wa2,
                                                unsigned short* __restrict__ WP) {
  const int t = threadIdx.x, b = blockIdx.x;
  if (b < 8) {
    __shared__ float p1[64][4], p2[64][4];
    const int kl = t >> 2, q = t & 3;
    const int k = b * 64 + kl;
    float s1 = 0.f, s2 = 0.f;
    for (int n = q * 64; n < q * 64 + 64; ++n) {
      float wv = W[(size_t)k * 256 + n];
      s1 += wv * a[n];
      s2 += wv * a[256 + n];
    }
    p1[kl][q] = s1; p2[kl][q] = s2;
    __syncthreads();
    if (t < 64) {
      wa1[b * 64 + t] = (p1[t][0] + p1[t][1]) + (p1[t][2] + p1[t][3]);
      wa2[b * 64 + t] = (p2[t][0] + p2[t][1]) + (p2[t][2] + p2[t][3]);
    }
  } else {
    const int wb = b - 8;
    const int l = t & 63, rep = t >> 6;
#pragma unroll
    for (int f = 0; f < 8; ++f) {
      const int fid = wb * 8 + f;
      const int n32 = fid >> 5, k16 = fid & 31;
#pragma unroll
      for (int ee = 0; ee < 2; ++ee) {
        const int e = rep * 2 + ee;
        WP[((size_t)(n32 * 32 + k16) * 64 + l) * 8 + e] =
            f2bf(W[(size_t)(k16 * 16 + (l >> 5) * 8 + e) * 256 + n32 * 32 + (l & 31)]);
      }
    }
  }
}

// ------------- Kernel A+M merged: maskpack (2048 blks) || gemmb (256 blks) --
// bid%9==0 -> MFMA bf16 gemm block (Wh_bf16 = bf16(h) @ bf16(W), fp32 acc);
// else mask block (r13-verbatim, transposed flush). The gemm is MFMA-based:
// block = 32 rows x 256 cols; wave w owns n-tiles 2w,2w+1. A-frag from h
// (2x float4 + 4 cvt_pk, shared rows across waves -> L1); B-frag from WP
// (coalesced 1KB). Fragment maps are the 13-round-verified ones.
__global__ __launch_bounds__(256, 2) void maskgemm(const int* __restrict__ adj,
                                                   unsigned long long* __restrict__ mask,
                                                   const float* __restrict__ h,
                                                   const unsigned short* __restrict__ WP,
                                                   unsigned short* __restrict__ whb) {
  __shared__ unsigned long long mbuf[4][128];  // (mask path)
  const int t = threadIdx.x;
  const int b = blockIdx.x;
  if (b % 9 == 0) {
    // ---- gemmb path ----
    const int gid = b / 9;            // 0..255
    const int m0 = gid * 32;
    const int w = t >> 6, lane = t & 63;
    const int am = lane & 31, asel = lane >> 5;
    f32x16 acc0 = {}, acc1 = {};
    const float* ap = h + (size_t)(m0 + am) * 512 + asel * 8;
    const unsigned short* wpa = WP + ((size_t)((2 * w) * 32) * 64 + lane) * 8;
    const unsigned short* wpb = WP + ((size_t)((2 * w + 1) * 32) * 64 + lane) * 8;
#pragma unroll 4
    for (int ks = 0; ks < 32; ++ks) {
      float4 a0 = *(const float4*)(ap + ks * 16);
      float4 a1v = *(const float4*)(ap + ks * 16 + 4);
      union { uint4 q; short8 s; } af;
      asm("v_cvt_pk_bf16_f32 %0, %1, %2" : "=v"(af.q.x) : "v"(a0.x), "v"(a0.y));
      asm("v_cvt_pk_bf16_f32 %0, %1, %2" : "=v"(af.q.y) : "v"(a0.z), "v"(a0.w));
      asm("v_cvt_pk_bf16_f32 %0, %1, %2" : "=v"(af.q.z) : "v"(a1v.x), "v"(a1v.y));
      asm("v_cvt_pk_bf16_f32 %0, %1, %2" : "=v"(af.q.w) : "v"(a1v.z), "v"(a1v.w));
      short8 b0 = *(const short8*)(wpa + (size_t)ks * 512);
      short8 b1 = *(const short8*)(wpb + (size_t)ks * 512);
      acc0 = __builtin_amdgcn_mfma_f32_32x32x16_bf16(af.s, b0, acc0, 0, 0, 0);
      acc1 = __builtin_amdgcn_mfma_f32_32x32x16_bf16(af.s, b1, acc1, 0, 0, 0);
    }
#pragma unroll
    for (int reg = 0; reg < 16; ++reg) {
      const int rowl = (reg & 3) + 8 * (reg >> 2) + 4 * asel;  // verified C/D map
      whb[(size_t)(m0 + rowl) * 256 + (2 * w) * 32 + am]     = f2bf(acc0[reg]);
      whb[(size_t)(m0 + rowl) * 256 + (2 * w + 1) * 32 + am] = f2bf(acc1[reg]);
    }
  } else {
    // ---- maskpack path (r13-verbatim, transposed flush) ----
    const int mask_id = b - b / 9 - 1;
    const int wave = t >> 6, lane = t & 63;
    const int row = mask_id * 4 + wave;
    const int* ap = adj + (size_t)row * 8192 + lane;
#pragma unroll 1
    for (int it0 = 0; it0 < 128; it0 += 4) {
      int a0 = ap[(it0 + 0) * 64];
      int a1 = ap[(it0 + 1) * 64];
      int a2 = ap[(it0 + 2) * 64];
      int a3 = ap[(it0 + 3) * 64];
      unsigned long long b0 = __ballot(a0 > 0);
      unsigned long long b1 = __ballot(a1 > 0);
      unsigned long long b2 = __ballot(a2 > 0);
      unsigned long long b3 = __ballot(a3 > 0);
      if (lane == 0) {
        mbuf[wave][it0 + 0] = b0; mbuf[wave][it0 + 1] = b1;
        mbuf[wave][it0 + 2] = b2; mbuf[wave][it0 + 3] = b3;
      }
    }
    __syncthreads();
    const int it = t & 127, half = t >> 7;
    const int row0 = mask_id * 4;
    unsigned long long tmp[2] = {mbuf[half * 2][it], mbuf[half * 2 + 1][it]};
    *(uint4*)&mask[(size_t)it * 8192 + row0 + half * 2] = *(const uint4*)tmp;
  }
}

// ------------- Kernel B: f1,f2,uvpack via f = h @ (W@a) ---------------------
// One wave per row (rowstats structure); dot h-row with wa1/wa2 instead of
// Wh-row with a. fp32 re-association only (~1e-6 on f1/f2).
__global__ __launch_bounds__(256) void fvec(const float* __restrict__ h,
                                            const float* __restrict__ wa1,
                                            const float* __restrict__ wa2,
                                            float* __restrict__ f1,
                                            float* __restrict__ f2,
                                            unsigned* __restrict__ uvpack) {
  const int t = threadIdx.x;
  const int w = t >> 6, lane = t & 63;
  const int i = blockIdx.x * 4 + w;
  const float* hp = h + (size_t)i * 512 + lane * 8;
  float4 h0 = *(const float4*)hp;
  float4 h1 = *(const float4*)(hp + 4);
  float4 wA0 = *(const float4*)&wa1[lane * 8];
  float4 wA1 = *(const float4*)&wa1[lane * 8 + 4];
  float4 wB0 = *(const float4*)&wa2[lane * 8];
  float4 wB1 = *(const float4*)&wa2[lane * 8 + 4];
  float s1 = h0.x * wA0.x + h0.y * wA0.y + h0.z * wA0.z + h0.w * wA0.w
           + h1.x * wA1.x + h1.y * wA1.y + h1.z * wA1.z + h1.w * wA1.w;
  float s2 = h0.x * wB0.x + h0.y * wB0.y + h0.z * wB0.z + h0.w * wB0.w
           + h1.x * wB1.x + h1.y * wB1.y + h1.z * wB1.z + h1.w * wB1.w;
#pragma unroll
  for (int off = 32; off; off >>= 1) { s1 += __shfl_xor(s1, off); s2 += __shfl_xor(s2, off); }
  if (lane == 0) {
    f1[i] = s1; f2[i] = s2;
    float u = __expf(s2), v = __expf(ALPHA * s2);
    uvpack[i] = (unsigned)f2bf(u) | ((unsigned)f2bf(v) << 16);
  }
}

// ------------- Kernel B2: pack Wh_bf16 into MFMA B-fragment layout ----------
// Same as r13 bpack but input is already bf16 (bit copy, no re-round).
// Reads are 64B-contiguous per half-wave; writes 16B/lane coalesced.
__global__ __launch_bounds__(256) void bpack(const unsigned short* __restrict__ whb,
                                             unsigned short* __restrict__ BP) {
  const int t = threadIdx.x, wave = t >> 6, lane = t & 63;
  const int c32 = blockIdx.x >> 4, sblk = blockIdx.x & 15;
  const int col = c32 * 32 + (lane & 31), hi = lane >> 5;
#pragma unroll
  for (int p = 0; p < 8; p++) {
    const int s = sblk * 32 + wave * 8 + p;
    unsigned short v[8];
#pragma unroll
    for (int e = 0; e < 8; e++)
      v[e] = whb[(size_t)(s * 16 + hi * 8 + e) * 256 + col];
    *(uint4*)&BP[((size_t)c32 * 512 + s) * 512 + lane * 8] = *(const uint4*)v;
  }
}

// ---------------- Kernel Bmax: F2max = max_j f2[j] --------------------------
__global__ __launch_bounds__(256) void f2max_k(const float* __restrict__ f2,
                                               float* __restrict__ f2maxp) {
  __shared__ float red[256];
  const int t = threadIdx.x;
  float m = -1e30f;
  for (int c = 0; c < 32; c++) m = fmaxf(m, f2[c * 256 + t]);
  red[t] = m;
  __syncthreads();
  for (int s = 128; s; s >>= 1) {
    if (t < s) red[t] = fmaxf(red[t], red[t + s]);
    __syncthreads();
  }
  if (t == 0) f2maxp[0] = red[0];
}

// ---------------- Kernel C: fused masked-softmax @ Wh (r13-VERBATIM) --------
// KEEP __launch_bounds__(256,1): (256,2) silently zeroes output (r10/r11).
#define LOADBF(BUF, SIDX)                                                        \
  {                                                                              \
    const int s_ = (SIDX) < 128 ? (SIDX) : 127;                                  \
    BUF[0] = *(const short8*)(bp0 + (size_t)(0 * 512 + s_) * 512);               \
    BUF[1] = *(const short8*)(bp0 + (size_t)(1 * 512 + s_) * 512);               \
    BUF[2] = *(const short8*)(bp0 + (size_t)(2 * 512 + s_) * 512);               \
    BUF[3] = *(const short8*)(bp0 + (size_t)(3 * 512 + s_) * 512);               \
  }

#define ATTN_SUB(KSUB, MWORD, UCA, UCB, BFC)                                     \
  {                                                                              \
    const unsigned mbyte_ = ((MWORD) >> (((KSUB) & 1) * 16 + aselsh)) & 0xFFu;   \
    const unsigned uu_[8] = {UCA.x, UCA.y, UCA.z, UCA.w, UCB.x, UCB.y, UCB.z, UCB.w}; \
    float w_[8];                                                                 \
    _Pragma("unroll")                                                            \
    for (int jj = 0; jj < 8; jj++) {                                             \
      union { unsigned u; float f; } cu_, cv_;                                   \
      cu_.u = uu_[jj] << 16;                                                     \
      cv_.u = uu_[jj] & 0xFFFF0000u;                                             \
      float wv_ = (cu_.f > Ui) ? Ai * cu_.f : Bi * cv_.f;                        \
      int ext_ = ((int)(mbyte_ << (31 - jj))) >> 31;   /* bit -> 0 / all-ones */ \
      union { float f; int i; } wu_; wu_.f = wv_; wu_.i &= ext_;                 \
      w_[jj] = wu_.f;                                                            \
    }                                                                            \
    lpriv += ((w_[0] + w_[1]) + (w_[2] + w_[3])) + ((w_[4] + w_[5]) + (w_[6] + w_[7])); \
    union { uint4 q; short8 s; } af_;                                            \
    asm("v_cvt_pk_bf16_f32 %0, %1, %2" : "=v"(af_.q.x) : "v"(w_[0]), "v"(w_[1]));\
    asm("v_cvt_pk_bf16_f32 %0, %1, %2" : "=v"(af_.q.y) : "v"(w_[2]), "v"(w_[3]));\
    asm("v_cvt_pk_bf16_f32 %0, %1, %2" : "=v"(af_.q.z) : "v"(w_[4]), "v"(w_[5]));\
    asm("v_cvt_pk_bf16_f32 %0, %1, %2" : "=v"(af_.q.w) : "v"(w_[6]), "v"(w_[7]));\
    acc[0] = __builtin_amdgcn_mfma_f32_32x32x16_bf16(af_.s, BFC[0], acc[0], 0, 0, 0); \
    acc[1] = __builtin_amdgcn_mfma_f32_32x32x16_bf16(af_.s, BFC[1], acc[1], 0, 0, 0); \
    acc[2] = __builtin_amdgcn_mfma_f32_32x32x16_bf16(af_.s, BFC[2], acc[2], 0, 0, 0); \
    acc[3] = __builtin_amdgcn_mfma_f32_32x32x16_bf16(af_.s, BFC[3], acc[3], 0, 0, 0); \
  }

#define ATTN_GROUP(G, UC, UN, MC, MN)                                            \
  {                                                                              \
    const int gn_ = (G) < 31 ? (G) + 1 : 31;                                     \
    MN = mp[(size_t)gn_ * 8192];                                                 \
    UN[0] = *(const uint4*)(uvp + gn_ * 64 + 0);                                 \
    UN[1] = *(const uint4*)(uvp + gn_ * 64 + 4);                                 \
    LOADBF(bfs2, 4 * (G) + 2);                                                   \
    LOADBF(bfs3, 4 * (G) + 3);                                                   \
    ATTN_SUB(0, MC.x, UC[0], UC[1], bfs0);                                       \
    UN[2] = *(const uint4*)(uvp + gn_ * 64 + 16);                                \
    UN[3] = *(const uint4*)(uvp + gn_ * 64 + 20);                                \
    ATTN_SUB(1, MC.x, UC[2], UC[3], bfs1);                                       \
    UN[4] = *(const uint4*)(uvp + gn_ * 64 + 32);                                \
    UN[5] = *(const uint4*)(uvp + gn_ * 64 + 36);                                \
    LOADBF(bfs0, 4 * (G) + 4);                                                   \
    LOADBF(bfs1, 4 * (G) + 5);                                                   \
    ATTN_SUB(2, MC.y, UC[4], UC[5], bfs2);                                       \
    UN[6] = *(const uint4*)(uvp + gn_ * 64 + 48);                                \
    UN[7] = *(const uint4*)(uvp + gn_ * 64 + 52);                                \
    ATTN_SUB(3, MC.y, UC[6], UC[7], bfs3);                                       \
  }

__global__ __launch_bounds__(256, 1) void attn_main(const unsigned long long* __restrict__ maskw,
                                                    const float* __restrict__ f1,
                                                    const unsigned* __restrict__ uvpack,
                                                    const unsigned short* __restrict__ BP,
                                                    const float* __restrict__ f2maxp,
                                                    float* __restrict__ out) {
  __shared__ float red[4][32][132];   // 4 jq x 32 rows x 128 cols (+4 pad); 67.6 KB
  __shared__ float lsum[4][32];
  const int t = threadIdx.x;
  const int wave = t >> 6, lane = t & 63;
  const int jq = wave;                  // each wave owns a j-quarter
  const int am = lane & 31, asel = lane >> 5;
  const int aselsh = asel * 8;
  const int bid = blockIdx.x;
  const int cg = bid & 1;               // col-group from block
  const int r0 = (bid >> 1) * 32;
  const int row = r0 + am;

  const float F2max = f2maxp[0];
  const float f1v = f1[row];
  const float x = f1v + F2max;
  const float M = x > 0.f ? x : ALPHA * x;   // analytic per-row max bound
  const float Ai = __expf(f1v - M);
  const float Bi = __expf(ALPHA * f1v - M);
  const float Ui = __expf(-f1v);             // u_j > Ui  <=>  f1_i + f2_j > 0

  f32x16 acc[4] = {};
  const uint2* mp = (const uint2*)maskw + (size_t)(jq * 32) * 8192 + row;
  const unsigned* uvp = uvpack + jq * 2048 + aselsh;
  const unsigned short* bp0 = BP + ((size_t)(cg * 4) * 512 + jq * 128) * 512 + lane * 8;

  uint2 mg = mp[0], mgN;
  uint4 ug[8], ugN[8];
#pragma unroll
  for (int k = 0; k < 4; k++) {
    ug[2 * k]     = *(const uint4*)(uvp + k * 16);
    ug[2 * k + 1] = *(const uint4*)(uvp + k * 16 + 4);
  }
  short8 bfs0[4], bfs1[4], bfs2[4], bfs3[4];
  LOADBF(bfs0, 0);
  LOADBF(bfs1, 1);
  float lpriv = 0.f;

#pragma unroll 1
  for (int gg = 0; gg < 16; ++gg) {
    ATTN_GROUP(2 * gg,     ug,  ugN, mg,  mgN);
    ATTN_GROUP(2 * gg + 1, ugN, ug,  mgN, mg);
  }

#pragma unroll
  for (int ct = 0; ct < 4; ct++) {
#pragma unroll
    for (int reg = 0; reg < 16; reg++) {
      const int rowl = (reg & 3) + 8 * (reg >> 2) + 4 * asel;  // verified C/D map
      red[jq][rowl][ct * 32 + am] = acc[ct][reg];
    }
  }
  lpriv += __shfl_xor(lpriv, 32);      // combine asel halves of row am
  if (asel == 0) lsum[jq][am] = lpriv;
  __syncthreads();

  const int rr = t >> 3, cb = (t & 7) * 16;
  const float l = lsum[0][rr] + lsum[1][rr] + lsum[2][rr] + lsum[3][rr];
  const float inv = 1.0f / fmaxf(l, 1e-30f);
#pragma unroll
  for (int cc = 0; cc < 16; cc += 4) {
    float4 v;
    v.x = red[0][rr][cb + cc + 0] + red[1][rr][cb + cc + 0] + red[2][rr][cb + cc + 0] + red[3][rr][cb + cc + 0];
    v.y = red[0][rr][cb + cc + 1] + red[1][rr][cb + cc + 1] + red[2][rr][cb + cc + 1] + red[3][rr][cb + cc + 1];
    v.z = red[0][rr][cb + cc + 2] + red[1][rr][cb + cc + 2] + red[2][rr][cb + cc + 2] + red[3][rr][cb + cc + 2];
    v.w = red[0][rr][cb + cc + 3] + red[1][rr][cb + cc + 3] + red[2][rr][cb + cc + 3] + red[3][rr][cb + cc + 3];
    v.x *= inv; v.y *= inv; v.z *= inv; v.w *= inv;
    float4 o;
    o.x = v.x > 0.f ? v.x : __expf(v.x) - 1.f;
    o.y = v.y > 0.f ? v.y : __expf(v.y) - 1.f;
    o.z = v.z > 0.f ? v.z : __expf(v.z) - 1.f;
    o.w = v.w > 0.f ? v.w : __expf(v.w) - 1.f;
    *(float4*)&out[(size_t)(r0 + rr) * 256 + cg * 128 + cb + cc] = o;
  }
}

extern "C" void kernel_launch(void* const* d_in, const int* in_sizes, int n_in,
                              void* d_out, int out_size, void* d_ws, size_t ws_size,
                              hipStream_t stream) {
  const float* h  = (const float*)d_in[0];
  const int* adj  = (const int*)d_in[1];
  const float* W  = (const float*)d_in[2];
  const float* a  = (const float*)d_in[3];
  float* out = (float*)d_out;
  char* ws = (char*)d_ws;

  // ws layout:
  //  [0, 4M):    whb bf16 (Wh in bf16, 4 MB)
  //  [4M, 4.25M): WP bf16 fragment-packed W (256 KB)
  //  [5M ...):   wa1 (2 KB), wa2 (2 KB @ 5M+4K)
  //  [8M, 16M):  mask_t bits (8 MB, [it][row])
  //  [16M, 20M): BP bf16 fragment-packed Wh (4 MB)
  //  [20M ...):  f1 (32K), f2 (32K), uvpack (32K), f2max (128B)
  unsigned short* whb  = (unsigned short*)ws;
  unsigned short* WP   = (unsigned short*)(ws + (size_t)(4u << 20));
  float* wa1           = (float*)(ws + (size_t)(5u << 20));
  float* wa2           = (float*)(ws + (size_t)(5u << 20) + (4u << 10));
  unsigned long long* mask = (unsigned long long*)(ws + (size_t)(8u << 20));
  unsigned short* BP   = (unsigned short*)(ws + (size_t)(16u << 20));
  float* f1            = (float*)(ws + (size_t)(20u << 20));
  float* f2            = (float*)(ws + (size_t)(20u << 20) + (32u << 10));
  unsigned* uvpack     = (unsigned*)(ws + (size_t)(20u << 20) + (64u << 10));
  float* f2maxp        = (float*)(ws + (size_t)(20u << 20) + (96u << 10));

  wa_wpack<<<40, 256, 0, stream>>>(W, a, wa1, wa2, WP);
  maskgemm<<<2304, 256, 0, stream>>>(adj, mask, h, WP, whb);
  fvec<<<2048, 256, 0, stream>>>(h, wa1, wa2, f1, f2, uvpack);
  bpack<<<128, 256, 0, stream>>>(whb, BP);
  f2max_k<<<1, 256, 0, stream>>>(f2, f2maxp);
  attn_main<<<512, 256, 0, stream>>>(mask, f1, uvpack, BP, f2maxp, out);
}